// Round 5
// baseline (1684.542 us; speedup 1.0000x reference)
//
#include <hip/hip_runtime.h>
#include <hip/hip_bf16.h>

#define NEG_SLOPE 0.2f
#define IN_DIM 256
#define C1 64
#define C2 32
#define ODIM 40
#define SCAN_CHUNK 4096  // 256 threads * 16 items

// ---------------- CSR build ----------------

__global__ void k_init_cnt(int* cnt, int n) {
    int i = blockIdx.x * 256 + threadIdx.x;
    if (i < n) cnt[i] = 1;  // start at 1: self-loop
}

__global__ void k_count(const int* __restrict__ dst, int E, int* __restrict__ cnt) {
    int i = blockIdx.x * 256 + threadIdx.x;
    if (i < E) atomicAdd(&cnt[dst[i]], 1);
}

__global__ void k_scan1(const int* __restrict__ cnt, int n, int* __restrict__ bsums) {
    __shared__ int lds[256];
    int t = threadIdx.x;
    int base = blockIdx.x * SCAN_CHUNK + t * 16;
    int s = 0;
#pragma unroll
    for (int i = 0; i < 16; i++) { int idx = base + i; s += (idx < n) ? cnt[idx] : 0; }
    lds[t] = s; __syncthreads();
    for (int off = 128; off > 0; off >>= 1) {
        if (t < off) lds[t] += lds[t + off];
        __syncthreads();
    }
    if (t == 0) bsums[blockIdx.x] = lds[0];
}

__global__ void k_scan2(int* bsums, int nb, int* row_ptr, int n, int total) {
    __shared__ int lds[256];
    int t = threadIdx.x;
    int v = (t < nb) ? bsums[t] : 0;
    lds[t] = v; __syncthreads();
    for (int off = 1; off < 256; off <<= 1) {
        int u = (t >= off) ? lds[t - off] : 0;
        __syncthreads();
        lds[t] += u;
        __syncthreads();
    }
    if (t < nb) bsums[t] = lds[t] - v;  // exclusive
    if (t == 0) row_ptr[n] = total;
}

__global__ void k_scan3(const int* __restrict__ cnt, int n, const int* __restrict__ bsums,
                        int* __restrict__ row_ptr) {
    __shared__ int lds[256];
    int t = threadIdx.x;
    int base = blockIdx.x * SCAN_CHUNK + t * 16;
    int loc[16];
    int s = 0;
#pragma unroll
    for (int i = 0; i < 16; i++) {
        int idx = base + i;
        int c = (idx < n) ? cnt[idx] : 0;
        loc[i] = s; s += c;
    }
    lds[t] = s; __syncthreads();
    for (int off = 1; off < 256; off <<= 1) {
        int u = (t >= off) ? lds[t - off] : 0;
        __syncthreads();
        lds[t] += u;
        __syncthreads();
    }
    int texcl = lds[t] - s + bsums[blockIdx.x];
#pragma unroll
    for (int i = 0; i < 16; i++) {
        int idx = base + i;
        if (idx < n) row_ptr[idx] = texcl + loc[i];
    }
}

__global__ void k_selfloop(const int* __restrict__ row_ptr, int n, int* __restrict__ adj,
                           int* __restrict__ cnt) {
    int i = blockIdx.x * 256 + threadIdx.x;
    if (i < n) { adj[row_ptr[i]] = i; cnt[i] = 1; }
}

__global__ void k_scatter(const int* __restrict__ src, const int* __restrict__ dst, int E,
                          const int* __restrict__ row_ptr, int* __restrict__ cnt,
                          int* __restrict__ adj) {
    int e = blockIdx.x * 256 + threadIdx.x;
    if (e < E) {
        int d = dst[e];
        int pos = row_ptr[d] + atomicAdd(&cnt[d], 1);
        adj[pos] = src[e];
    }
}

// ---------------- GEMM1: h1 = x @ W1, plus alpha_src/alpha_dst ----------------
// K-tiled: W1 staged in 64k x 64c LDS chunks (16 KB -> 8 blocks/CU).
// Block 256 = 4 waves; wave = 16 rows; lane = output column.

__global__ __launch_bounds__(256, 8)
void k_gemm1(const float* __restrict__ x, const float* __restrict__ W1,
             const float* __restrict__ attS, const float* __restrict__ attD,
             float* __restrict__ h1, float* __restrict__ as1, float* __restrict__ ad1, int n) {
    __shared__ float wt[64 * C1];  // [k][c] for current K-chunk; reads are conflict-free
    int t = threadIdx.x;
    int wave = t >> 6, lane = t & 63;
    int row0 = blockIdx.x * 64 + wave * 16;

    const float* xb[16];
#pragma unroll
    for (int r = 0; r < 16; r++) {
        int row = row0 + r; if (row >= n) row = n - 1;  // clamp tail loads
        xb[r] = x + (size_t)row * IN_DIM;
    }
    float acc[16];
#pragma unroll
    for (int r = 0; r < 16; r++) acc[r] = 0.f;

    for (int k0 = 0; k0 < IN_DIM; k0 += 64) {
        if (k0) __syncthreads();
        // stage W1[k0..k0+64)[0..64) -> wt, coalesced global / conflict-free LDS writes
#pragma unroll
        for (int j = 0; j < 16; j++) {
            int flat = j * 256 + t;
            wt[flat] = W1[(size_t)(k0 + (flat >> 6)) * C1 + (flat & 63)];
        }
        __syncthreads();
        for (int k = 0; k < 64; k += 4) {
            float4 xv[16];
#pragma unroll
            for (int r = 0; r < 16; r++)
                xv[r] = *(const float4*)&xb[r][k0 + k];  // wave-uniform broadcast
            float w0 = wt[(k + 0) * C1 + lane];
            float w1 = wt[(k + 1) * C1 + lane];
            float w2 = wt[(k + 2) * C1 + lane];
            float w3 = wt[(k + 3) * C1 + lane];
#pragma unroll
            for (int r = 0; r < 16; r++) {
                acc[r] = fmaf(xv[r].x, w0, acc[r]);
                acc[r] = fmaf(xv[r].y, w1, acc[r]);
                acc[r] = fmaf(xv[r].z, w2, acc[r]);
                acc[r] = fmaf(xv[r].w, w3, acc[r]);
            }
        }
    }

    float aS = attS[lane], aD = attD[lane];
#pragma unroll
    for (int r = 0; r < 16; r++) {
        int row = row0 + r;
        if (row >= n) break;
        float h = acc[r];
        h1[(size_t)row * C1 + lane] = h;
        float vs = h * aS, vd = h * aD;
#pragma unroll
        for (int off = 32; off > 0; off >>= 1) {
            vs += __shfl_xor(vs, off);
            vd += __shfl_xor(vd, off);
        }
        if (lane == 0) { as1[row] = vs; ad1[row] = vd; }
    }
}

// ---------------- Layer-1 aggregation: one wave per dst node, lane = channel ----------------

__global__ __launch_bounds__(256)
void k_agg1(const float* __restrict__ h1, const float* __restrict__ as1,
            const float* __restrict__ ad1, const int* __restrict__ row_ptr,
            const int* __restrict__ adj, const float* __restrict__ b1,
            float* __restrict__ h1out, int n) {
    int wave = (blockIdx.x * 256 + threadIdx.x) >> 6;
    int lane = threadIdx.x & 63;
    if (wave >= n) return;
    int d = wave;
    int beg = row_ptr[d], end = row_ptr[d + 1];
    float adv = ad1[d];
    float acc = 0.f, dsum = 0.f;
    for (int base = beg; base < end; base += 64) {
        int cnt = min(64, end - base);
        int s = d; float w = 0.f;
        if (lane < cnt) {
            s = adj[base + lane];
            float lg = as1[s] + adv;
            lg = lg > 0.f ? lg : NEG_SLOPE * lg;
            w = expf(lg);
            dsum += w;
        }
        int j = 0;
        for (; j + 4 <= cnt; j += 4) {
            int s0 = __shfl(s, j),     s1 = __shfl(s, j + 1);
            int s2 = __shfl(s, j + 2), s3 = __shfl(s, j + 3);
            float w0 = __shfl(w, j),     w1 = __shfl(w, j + 1);
            float w2 = __shfl(w, j + 2), w3 = __shfl(w, j + 3);
            float g0 = h1[(size_t)s0 * C1 + lane];
            float g1 = h1[(size_t)s1 * C1 + lane];
            float g2 = h1[(size_t)s2 * C1 + lane];
            float g3 = h1[(size_t)s3 * C1 + lane];
            acc = fmaf(w0, g0, acc); acc = fmaf(w1, g1, acc);
            acc = fmaf(w2, g2, acc); acc = fmaf(w3, g3, acc);
        }
        for (; j < cnt; j++) {
            int sj = __shfl(s, j);
            float wj = __shfl(w, j);
            acc = fmaf(wj, h1[(size_t)sj * C1 + lane], acc);
        }
    }
#pragma unroll
    for (int off = 32; off > 0; off >>= 1) dsum += __shfl_xor(dsum, off);
    float out = acc / dsum + b1[lane];
    h1out[(size_t)d * C1 + lane] = out > 0.f ? out : 0.f;
}

// ---------------- GEMM2 + alpha2 ----------------
// block 256 (4 waves); each wave: lane -> (half, col), 2 rows at a time, 8 rows total.

__global__ __launch_bounds__(256)
void k_gemm2(const float* __restrict__ h1out, const float* __restrict__ W2,
             const float* __restrict__ attS, const float* __restrict__ attD,
             float* __restrict__ h2, float* __restrict__ as2, float* __restrict__ ad2, int n) {
    __shared__ float w2t[C2 * 68];
    __shared__ float sAttS[C2], sAttD[C2];
    int t = threadIdx.x;
    for (int i = t; i < C1 * C2; i += 256) {
        int k = i >> 5, c = i & 31;
        w2t[c * 68 + k] = W2[i];
    }
    if (t < C2) { sAttS[t] = attS[t]; sAttD[t] = attD[t]; }
    __syncthreads();
    int wave = t >> 6, lane = t & 63;
    int col = lane & 31, half = lane >> 5;
    int rowbase = blockIdx.x * 32 + wave * 8;
    const float* wrow = &w2t[col * 68];
    for (int rr = 0; rr < 8; rr += 2) {
        int row = rowbase + rr + half;
        if (row >= n) return;
        float acc = 0.f;
#pragma unroll
        for (int k = 0; k < C1; k += 4) {
            float4 wv = *(const float4*)&wrow[k];
            float4 xv = *(const float4*)&h1out[(size_t)row * C1 + k];
            acc = fmaf(xv.x, wv.x, acc);
            acc = fmaf(xv.y, wv.y, acc);
            acc = fmaf(xv.z, wv.z, acc);
            acc = fmaf(xv.w, wv.w, acc);
        }
        h2[(size_t)row * C2 + col] = acc;
        float vs = acc * sAttS[col], vd = acc * sAttD[col];
#pragma unroll
        for (int off = 16; off > 0; off >>= 1) {
            vs += __shfl_xor(vs, off);
            vd += __shfl_xor(vd, off);
        }
        if (col == 0) { as2[row] = vs; ad2[row] = vd; }
    }
}

// ---------------- Layer-2 aggregation + bias + relu -> emb (d_out) ----------------
// one wave per node; lane -> (half, c); two edges per iteration.

__global__ __launch_bounds__(256)
void k_agg2(const float* __restrict__ h2, const float* __restrict__ as2,
            const float* __restrict__ ad2, const int* __restrict__ row_ptr,
            const int* __restrict__ adj, const float* __restrict__ b2,
            float* __restrict__ emb, int n) {
    int wave = (blockIdx.x * 256 + threadIdx.x) >> 6;
    int lane = threadIdx.x & 63;
    if (wave >= n) return;
    int d = wave;
    int beg = row_ptr[d], end = row_ptr[d + 1];
    float adv = ad2[d];
    int c = lane & 31, half = lane >> 5;
    float acc = 0.f, dsum = 0.f;
    for (int base = beg; base < end; base += 64) {
        int cnt = min(64, end - base);
        int s = d; float w = 0.f;
        if (lane < cnt) {
            s = adj[base + lane];
            float lg = as2[s] + adv;
            lg = lg > 0.f ? lg : NEG_SLOPE * lg;
            w = expf(lg);
            dsum += w;
        }
        int j = 0;
        for (; j + 4 <= cnt; j += 4) {
            int sa = __shfl(s, j + half);
            int sb = __shfl(s, j + 2 + half);
            float wa = __shfl(w, j + half);
            float wb = __shfl(w, j + 2 + half);
            float ga = h2[(size_t)sa * C2 + c];
            float gb = h2[(size_t)sb * C2 + c];
            acc = fmaf(wa, ga, acc);
            acc = fmaf(wb, gb, acc);
        }
        for (; j + 2 <= cnt; j += 2) {
            int sj = __shfl(s, j + half);
            float wj = __shfl(w, j + half);
            acc = fmaf(wj, h2[(size_t)sj * C2 + c], acc);
        }
        if (j < cnt) {  // single leftover edge: half 0 only
            int sj = __shfl(s, j);
            float wj = __shfl(w, j);
            if (half == 0) acc = fmaf(wj, h2[(size_t)sj * C2 + c], acc);
        }
    }
    acc += __shfl_xor(acc, 32);
#pragma unroll
    for (int off = 32; off > 0; off >>= 1) dsum += __shfl_xor(dsum, off);
    if (half == 0) {
        float v = acc / dsum + b2[c];
        emb[(size_t)d * C2 + c] = v > 0.f ? v : 0.f;
    }
}

// ---------------- logits = emb @ fcW + fcb ----------------

__global__ __launch_bounds__(256)
void k_logits(const float* __restrict__ emb, const float* __restrict__ fcW,
              const float* __restrict__ fcb, float* __restrict__ out, int n) {
    __shared__ float w[C2 * ODIM];
    __shared__ float b[ODIM];
    int t = threadIdx.x;
    for (int i = t; i < C2 * ODIM; i += 256) w[i] = fcW[i];
    if (t < ODIM) b[t] = fcb[t];
    __syncthreads();
    int lane = t & 63;
    int row = blockIdx.x * 4 + (t >> 6);
    if (row >= n) return;
    float acc = (lane < ODIM) ? b[lane] : 0.f;
    const float4* er = (const float4*)&emb[(size_t)row * C2];
#pragma unroll
    for (int c4 = 0; c4 < 8; c4++) {
        float4 e = er[c4];
        int c = c4 * 4;
        if (lane < ODIM) {
            acc = fmaf(e.x, w[(c + 0) * ODIM + lane], acc);
            acc = fmaf(e.y, w[(c + 1) * ODIM + lane], acc);
            acc = fmaf(e.z, w[(c + 2) * ODIM + lane], acc);
            acc = fmaf(e.w, w[(c + 3) * ODIM + lane], acc);
        }
    }
    if (lane < ODIM) out[(size_t)row * ODIM + lane] = acc;
}

// ---------------- launch ----------------

extern "C" void kernel_launch(void* const* d_in, const int* in_sizes, int n_in,
                              void* d_out, int out_size, void* d_ws, size_t ws_size,
                              hipStream_t stream) {
    const float* x    = (const float*)d_in[0];
    const int*   ei   = (const int*)d_in[1];
    const float* W1   = (const float*)d_in[2];
    const float* aS1  = (const float*)d_in[3];
    const float* aD1  = (const float*)d_in[4];
    const float* b1   = (const float*)d_in[5];
    const float* W2   = (const float*)d_in[6];
    const float* aS2  = (const float*)d_in[7];
    const float* aD2  = (const float*)d_in[8];
    const float* b2   = (const float*)d_in[9];
    const float* fcW  = (const float*)d_in[10];
    const float* fcb  = (const float*)d_in[11];

    const int N = in_sizes[0] / IN_DIM;
    const int E = in_sizes[1] / 2;
    const int* src = ei;
    const int* dst = ei + E;

    // workspace layout (floats/ints)
    float* h1    = (float*)d_ws;               // N*64
    float* h1out = h1 + (size_t)N * C1;        // N*64
    float* as1   = h1out + (size_t)N * C1;     // N
    float* ad1   = as1 + N;
    float* as2   = ad1 + N;
    float* ad2   = as2 + N;
    int*   cnt   = (int*)(ad2 + N);            // N
    int*   row_ptr = cnt + N;                  // N+1
    int*   bsums   = row_ptr + (N + 1);        // <=256
    int*   adj     = bsums + 256;              // E+N
    float* h2    = h1;                         // alias: h1 dead after k_agg1

    float* emb    = (float*)d_out;             // N*32
    float* logits = emb + (size_t)N * C2;      // N*40

    int nbN   = (N + 255) / 256;
    int nbE   = (E + 255) / 256;
    int nbS   = (N + SCAN_CHUNK - 1) / SCAN_CHUNK;  // 25

    k_init_cnt<<<nbN, 256, 0, stream>>>(cnt, N);
    k_count<<<nbE, 256, 0, stream>>>(dst, E, cnt);
    k_scan1<<<nbS, 256, 0, stream>>>(cnt, N, bsums);
    k_scan2<<<1, 256, 0, stream>>>(bsums, nbS, row_ptr, N, E + N);
    k_scan3<<<nbS, 256, 0, stream>>>(cnt, N, bsums, row_ptr);
    k_selfloop<<<nbN, 256, 0, stream>>>(row_ptr, N, adj, cnt);
    k_scatter<<<nbE, 256, 0, stream>>>(src, dst, E, row_ptr, cnt, adj);

    int nbG1 = (N + 63) / 64;
    k_gemm1<<<nbG1, 256, 0, stream>>>(x, W1, aS1, aD1, h1, as1, ad1, N);
    int nbA = (N + 3) / 4;
    k_agg1<<<nbA, 256, 0, stream>>>(h1, as1, ad1, row_ptr, adj, b1, h1out, N);
    int nbG2 = (N + 31) / 32;
    k_gemm2<<<nbG2, 256, 0, stream>>>(h1out, W2, aS2, aD2, h2, as2, ad2, N);
    k_agg2<<<nbA, 256, 0, stream>>>(h2, as2, ad2, row_ptr, adj, b2, emb, N);
    k_logits<<<nbA, 256, 0, stream>>>(emb, fcW, fcb, logits, N);
}

// Round 6
// 695.005 us; speedup vs baseline: 2.4238x; 2.4238x over previous
//
#include <hip/hip_runtime.h>
#include <hip/hip_bf16.h>

#define NEG_SLOPE 0.2f
#define IN_DIM 256
#define C1 64
#define C2 32
#define ODIM 40
#define SCAN_CHUNK 4096  // 256 threads * 16 items

// ---------------- CSR build ----------------

__global__ void k_init_cnt(int* cnt, int n) {
    int i = blockIdx.x * 256 + threadIdx.x;
    if (i < n) cnt[i] = 1;  // start at 1: self-loop
}

__global__ void k_count(const int* __restrict__ dst, int E, int* __restrict__ cnt) {
    int i = blockIdx.x * 256 + threadIdx.x;
    if (i < E) atomicAdd(&cnt[dst[i]], 1);
}

__global__ void k_scan1(const int* __restrict__ cnt, int n, int* __restrict__ bsums) {
    __shared__ int lds[256];
    int t = threadIdx.x;
    int base = blockIdx.x * SCAN_CHUNK + t * 16;
    int s = 0;
#pragma unroll
    for (int i = 0; i < 16; i++) { int idx = base + i; s += (idx < n) ? cnt[idx] : 0; }
    lds[t] = s; __syncthreads();
    for (int off = 128; off > 0; off >>= 1) {
        if (t < off) lds[t] += lds[t + off];
        __syncthreads();
    }
    if (t == 0) bsums[blockIdx.x] = lds[0];
}

__global__ void k_scan2(int* bsums, int nb, int* row_ptr, int n, int total) {
    __shared__ int lds[256];
    int t = threadIdx.x;
    int v = (t < nb) ? bsums[t] : 0;
    lds[t] = v; __syncthreads();
    for (int off = 1; off < 256; off <<= 1) {
        int u = (t >= off) ? lds[t - off] : 0;
        __syncthreads();
        lds[t] += u;
        __syncthreads();
    }
    if (t < nb) bsums[t] = lds[t] - v;  // exclusive
    if (t == 0) row_ptr[n] = total;
}

__global__ void k_scan3(const int* __restrict__ cnt, int n, const int* __restrict__ bsums,
                        int* __restrict__ row_ptr) {
    __shared__ int lds[256];
    int t = threadIdx.x;
    int base = blockIdx.x * SCAN_CHUNK + t * 16;
    int loc[16];
    int s = 0;
#pragma unroll
    for (int i = 0; i < 16; i++) {
        int idx = base + i;
        int c = (idx < n) ? cnt[idx] : 0;
        loc[i] = s; s += c;
    }
    lds[t] = s; __syncthreads();
    for (int off = 1; off < 256; off <<= 1) {
        int u = (t >= off) ? lds[t - off] : 0;
        __syncthreads();
        lds[t] += u;
        __syncthreads();
    }
    int texcl = lds[t] - s + bsums[blockIdx.x];
#pragma unroll
    for (int i = 0; i < 16; i++) {
        int idx = base + i;
        if (idx < n) row_ptr[idx] = texcl + loc[i];
    }
}

__global__ void k_selfloop(const int* __restrict__ row_ptr, int n, int* __restrict__ adj,
                           int* __restrict__ cnt) {
    int i = blockIdx.x * 256 + threadIdx.x;
    if (i < n) { adj[row_ptr[i]] = i; cnt[i] = 1; }
}

__global__ void k_scatter(const int* __restrict__ src, const int* __restrict__ dst, int E,
                          const int* __restrict__ row_ptr, int* __restrict__ cnt,
                          int* __restrict__ adj) {
    int e = blockIdx.x * 256 + threadIdx.x;
    if (e < E) {
        int d = dst[e];
        int pos = row_ptr[d] + atomicAdd(&cnt[d], 1);
        adj[pos] = src[e];
    }
}

// ---------------- GEMM1: h1 = x @ W1 ----------------
// lane = row (coalesced x loads, 64B/lane/chunk); block-uniform column half
// so W1 reads are wave-uniform -> SGPR loads + v_fma with scalar operand.
// acc[32] + 4x float4 ~ 60 VGPR: no spill risk under (256,4).

__global__ __launch_bounds__(256, 4)
void k_gemm1(const float* __restrict__ x, const float* __restrict__ W1,
             float* __restrict__ h1, int n) {
    int t = threadIdx.x;
    int wave = t >> 6, lane = t & 63;
    int chalf = (blockIdx.x & 1) * 32;                  // block-uniform column half
    int row = (blockIdx.x >> 1) * 256 + wave * 64 + lane;
    bool active = row < n;
    int rowc = active ? row : n - 1;
    const float4* xr = (const float4*)(x + (size_t)rowc * IN_DIM);

    float acc[32];
#pragma unroll
    for (int c = 0; c < 32; c++) acc[c] = 0.f;

#define FMA_K(XC, KK) { \
        const float* wk = wb + (KK) * C1; \
        _Pragma("unroll") \
        for (int c = 0; c < 32; c++) acc[c] = fmaf((XC), wk[c], acc[c]); }

    for (int k0 = 0; k0 < 16; k0++) {                   // BK = 16
        float4 xv0 = xr[k0 * 4 + 0];
        float4 xv1 = xr[k0 * 4 + 1];
        float4 xv2 = xr[k0 * 4 + 2];
        float4 xv3 = xr[k0 * 4 + 3];
        const float* wb = W1 + (size_t)(k0 * 16) * C1 + chalf;  // uniform
        FMA_K(xv0.x, 0)  FMA_K(xv0.y, 1)  FMA_K(xv0.z, 2)  FMA_K(xv0.w, 3)
        FMA_K(xv1.x, 4)  FMA_K(xv1.y, 5)  FMA_K(xv1.z, 6)  FMA_K(xv1.w, 7)
        FMA_K(xv2.x, 8)  FMA_K(xv2.y, 9)  FMA_K(xv2.z, 10) FMA_K(xv2.w, 11)
        FMA_K(xv3.x, 12) FMA_K(xv3.y, 13) FMA_K(xv3.z, 14) FMA_K(xv3.w, 15)
    }
#undef FMA_K

    if (!active) return;
    float* hp = h1 + (size_t)row * C1 + chalf;
#pragma unroll
    for (int j = 0; j < 8; j++)
        *(float4*)(hp + j * 4) =
            make_float4(acc[j * 4], acc[j * 4 + 1], acc[j * 4 + 2], acc[j * 4 + 3]);
}

// ---------------- alpha_src / alpha_dst for layer 1 (wave per row) ----------------

__global__ __launch_bounds__(256)
void k_alpha(const float* __restrict__ h, const float* __restrict__ attS,
             const float* __restrict__ attD, float* __restrict__ as_,
             float* __restrict__ ad_, int n) {
    int wave = (blockIdx.x * 256 + threadIdx.x) >> 6;
    int lane = threadIdx.x & 63;
    if (wave >= n) return;
    float hv = h[(size_t)wave * C1 + lane];
    float vs = hv * attS[lane], vd = hv * attD[lane];
#pragma unroll
    for (int off = 32; off > 0; off >>= 1) {
        vs += __shfl_xor(vs, off);
        vd += __shfl_xor(vd, off);
    }
    if (lane == 0) { as_[wave] = vs; ad_[wave] = vd; }
}

// ---------------- Layer-1 aggregation: one wave per dst node, lane = channel ----------------

__global__ __launch_bounds__(256)
void k_agg1(const float* __restrict__ h1, const float* __restrict__ as1,
            const float* __restrict__ ad1, const int* __restrict__ row_ptr,
            const int* __restrict__ adj, const float* __restrict__ b1,
            float* __restrict__ h1out, int n) {
    int wave = (blockIdx.x * 256 + threadIdx.x) >> 6;
    int lane = threadIdx.x & 63;
    if (wave >= n) return;
    int d = wave;
    int beg = row_ptr[d], end = row_ptr[d + 1];
    float adv = ad1[d];
    float acc = 0.f, dsum = 0.f;
    for (int base = beg; base < end; base += 64) {
        int cnt = min(64, end - base);
        int s = d; float w = 0.f;
        if (lane < cnt) {
            s = adj[base + lane];
            float lg = as1[s] + adv;
            lg = lg > 0.f ? lg : NEG_SLOPE * lg;
            w = expf(lg);
            dsum += w;
        }
        int j = 0;
        for (; j + 4 <= cnt; j += 4) {
            int s0 = __shfl(s, j),     s1 = __shfl(s, j + 1);
            int s2 = __shfl(s, j + 2), s3 = __shfl(s, j + 3);
            float w0 = __shfl(w, j),     w1 = __shfl(w, j + 1);
            float w2 = __shfl(w, j + 2), w3 = __shfl(w, j + 3);
            float g0 = h1[(size_t)s0 * C1 + lane];
            float g1 = h1[(size_t)s1 * C1 + lane];
            float g2 = h1[(size_t)s2 * C1 + lane];
            float g3 = h1[(size_t)s3 * C1 + lane];
            acc = fmaf(w0, g0, acc); acc = fmaf(w1, g1, acc);
            acc = fmaf(w2, g2, acc); acc = fmaf(w3, g3, acc);
        }
        for (; j < cnt; j++) {
            int sj = __shfl(s, j);
            float wj = __shfl(w, j);
            acc = fmaf(wj, h1[(size_t)sj * C1 + lane], acc);
        }
    }
#pragma unroll
    for (int off = 32; off > 0; off >>= 1) dsum += __shfl_xor(dsum, off);
    float out = acc / dsum + b1[lane];
    h1out[(size_t)d * C1 + lane] = out > 0.f ? out : 0.f;
}

// ---------------- GEMM2 + alpha2 ----------------
// block 256 (4 waves); each wave: lane -> (half, col), 2 rows at a time, 8 rows total.

__global__ __launch_bounds__(256)
void k_gemm2(const float* __restrict__ h1out, const float* __restrict__ W2,
             const float* __restrict__ attS, const float* __restrict__ attD,
             float* __restrict__ h2, float* __restrict__ as2, float* __restrict__ ad2, int n) {
    __shared__ float w2t[C2 * 68];
    __shared__ float sAttS[C2], sAttD[C2];
    int t = threadIdx.x;
    for (int i = t; i < C1 * C2; i += 256) {
        int k = i >> 5, c = i & 31;
        w2t[c * 68 + k] = W2[i];
    }
    if (t < C2) { sAttS[t] = attS[t]; sAttD[t] = attD[t]; }
    __syncthreads();
    int wave = t >> 6, lane = t & 63;
    int col = lane & 31, half = lane >> 5;
    int rowbase = blockIdx.x * 32 + wave * 8;
    const float* wrow = &w2t[col * 68];
    for (int rr = 0; rr < 8; rr += 2) {
        int row = rowbase + rr + half;
        if (row >= n) return;
        float acc = 0.f;
#pragma unroll
        for (int k = 0; k < C1; k += 4) {
            float4 wv = *(const float4*)&wrow[k];
            float4 xv = *(const float4*)&h1out[(size_t)row * C1 + k];
            acc = fmaf(xv.x, wv.x, acc);
            acc = fmaf(xv.y, wv.y, acc);
            acc = fmaf(xv.z, wv.z, acc);
            acc = fmaf(xv.w, wv.w, acc);
        }
        h2[(size_t)row * C2 + col] = acc;
        float vs = acc * sAttS[col], vd = acc * sAttD[col];
#pragma unroll
        for (int off = 16; off > 0; off >>= 1) {
            vs += __shfl_xor(vs, off);
            vd += __shfl_xor(vd, off);
        }
        if (col == 0) { as2[row] = vs; ad2[row] = vd; }
    }
}

// ---------------- Layer-2 aggregation + bias + relu -> emb (d_out) ----------------
// one wave per node; lane -> (half, c); two edges per iteration.

__global__ __launch_bounds__(256)
void k_agg2(const float* __restrict__ h2, const float* __restrict__ as2,
            const float* __restrict__ ad2, const int* __restrict__ row_ptr,
            const int* __restrict__ adj, const float* __restrict__ b2,
            float* __restrict__ emb, int n) {
    int wave = (blockIdx.x * 256 + threadIdx.x) >> 6;
    int lane = threadIdx.x & 63;
    if (wave >= n) return;
    int d = wave;
    int beg = row_ptr[d], end = row_ptr[d + 1];
    float adv = ad2[d];
    int c = lane & 31, half = lane >> 5;
    float acc = 0.f, dsum = 0.f;
    for (int base = beg; base < end; base += 64) {
        int cnt = min(64, end - base);
        int s = d; float w = 0.f;
        if (lane < cnt) {
            s = adj[base + lane];
            float lg = as2[s] + adv;
            lg = lg > 0.f ? lg : NEG_SLOPE * lg;
            w = expf(lg);
            dsum += w;
        }
        int j = 0;
        for (; j + 4 <= cnt; j += 4) {
            int sa = __shfl(s, j + half);
            int sb = __shfl(s, j + 2 + half);
            float wa = __shfl(w, j + half);
            float wb = __shfl(w, j + 2 + half);
            float ga = h2[(size_t)sa * C2 + c];
            float gb = h2[(size_t)sb * C2 + c];
            acc = fmaf(wa, ga, acc);
            acc = fmaf(wb, gb, acc);
        }
        for (; j + 2 <= cnt; j += 2) {
            int sj = __shfl(s, j + half);
            float wj = __shfl(w, j + half);
            acc = fmaf(wj, h2[(size_t)sj * C2 + c], acc);
        }
        if (j < cnt) {  // single leftover edge: half 0 only
            int sj = __shfl(s, j);
            float wj = __shfl(w, j);
            if (half == 0) acc = fmaf(wj, h2[(size_t)sj * C2 + c], acc);
        }
    }
    acc += __shfl_xor(acc, 32);
#pragma unroll
    for (int off = 32; off > 0; off >>= 1) dsum += __shfl_xor(dsum, off);
    if (half == 0) {
        float v = acc / dsum + b2[c];
        emb[(size_t)d * C2 + c] = v > 0.f ? v : 0.f;
    }
}

// ---------------- logits = emb @ fcW + fcb ----------------

__global__ __launch_bounds__(256)
void k_logits(const float* __restrict__ emb, const float* __restrict__ fcW,
              const float* __restrict__ fcb, float* __restrict__ out, int n) {
    __shared__ float w[C2 * ODIM];
    __shared__ float b[ODIM];
    int t = threadIdx.x;
    for (int i = t; i < C2 * ODIM; i += 256) w[i] = fcW[i];
    if (t < ODIM) b[t] = fcb[t];
    __syncthreads();
    int lane = t & 63;
    int row = blockIdx.x * 4 + (t >> 6);
    if (row >= n) return;
    float acc = (lane < ODIM) ? b[lane] : 0.f;
    const float4* er = (const float4*)&emb[(size_t)row * C2];
#pragma unroll
    for (int c4 = 0; c4 < 8; c4++) {
        float4 e = er[c4];
        int c = c4 * 4;
        if (lane < ODIM) {
            acc = fmaf(e.x, w[(c + 0) * ODIM + lane], acc);
            acc = fmaf(e.y, w[(c + 1) * ODIM + lane], acc);
            acc = fmaf(e.z, w[(c + 2) * ODIM + lane], acc);
            acc = fmaf(e.w, w[(c + 3) * ODIM + lane], acc);
        }
    }
    if (lane < ODIM) out[(size_t)row * ODIM + lane] = acc;
}

// ---------------- launch ----------------

extern "C" void kernel_launch(void* const* d_in, const int* in_sizes, int n_in,
                              void* d_out, int out_size, void* d_ws, size_t ws_size,
                              hipStream_t stream) {
    const float* x    = (const float*)d_in[0];
    const int*   ei   = (const int*)d_in[1];
    const float* W1   = (const float*)d_in[2];
    const float* aS1  = (const float*)d_in[3];
    const float* aD1  = (const float*)d_in[4];
    const float* b1   = (const float*)d_in[5];
    const float* W2   = (const float*)d_in[6];
    const float* aS2  = (const float*)d_in[7];
    const float* aD2  = (const float*)d_in[8];
    const float* b2   = (const float*)d_in[9];
    const float* fcW  = (const float*)d_in[10];
    const float* fcb  = (const float*)d_in[11];

    const int N = in_sizes[0] / IN_DIM;
    const int E = in_sizes[1] / 2;
    const int* src = ei;
    const int* dst = ei + E;

    // workspace layout (floats/ints)
    float* h1    = (float*)d_ws;               // N*64
    float* h1out = h1 + (size_t)N * C1;        // N*64
    float* as1   = h1out + (size_t)N * C1;     // N
    float* ad1   = as1 + N;
    float* as2   = ad1 + N;
    float* ad2   = as2 + N;
    int*   cnt   = (int*)(ad2 + N);            // N
    int*   row_ptr = cnt + N;                  // N+1
    int*   bsums   = row_ptr + (N + 1);        // <=256
    int*   adj     = bsums + 256;              // E+N
    float* h2    = h1;                         // alias: h1 dead after k_agg1

    float* emb    = (float*)d_out;             // N*32
    float* logits = emb + (size_t)N * C2;      // N*40

    int nbN   = (N + 255) / 256;
    int nbE   = (E + 255) / 256;
    int nbS   = (N + SCAN_CHUNK - 1) / SCAN_CHUNK;  // 25

    k_init_cnt<<<nbN, 256, 0, stream>>>(cnt, N);
    k_count<<<nbE, 256, 0, stream>>>(dst, E, cnt);
    k_scan1<<<nbS, 256, 0, stream>>>(cnt, N, bsums);
    k_scan2<<<1, 256, 0, stream>>>(bsums, nbS, row_ptr, N, E + N);
    k_scan3<<<nbS, 256, 0, stream>>>(cnt, N, bsums, row_ptr);
    k_selfloop<<<nbN, 256, 0, stream>>>(row_ptr, N, adj, cnt);
    k_scatter<<<nbE, 256, 0, stream>>>(src, dst, E, row_ptr, cnt, adj);

    int nbG1 = 2 * ((N + 255) / 256);   // x2: column halves
    k_gemm1<<<nbG1, 256, 0, stream>>>(x, W1, h1, N);
    int nbA = (N + 3) / 4;
    k_alpha<<<nbA, 256, 0, stream>>>(h1, aS1, aD1, as1, ad1, N);
    k_agg1<<<nbA, 256, 0, stream>>>(h1, as1, ad1, row_ptr, adj, b1, h1out, N);
    int nbG2 = (N + 31) / 32;
    k_gemm2<<<nbG2, 256, 0, stream>>>(h1out, W2, aS2, aD2, h2, as2, ad2, N);
    k_agg2<<<nbA, 256, 0, stream>>>(h2, as2, ad2, row_ptr, adj, b2, emb, N);
    k_logits<<<nbA, 256, 0, stream>>>(emb, fcW, fcb, logits, N);
}